// Round 19
// baseline (234.583 us; speedup 1.0000x reference)
//
#include <hip/hip_runtime.h>
#include <hip/hip_bf16.h>

#define B_SZ   2
#define LSEQ   1024
#define DD     8
#define DCTRL  256
#define POLY   40
#define NL     2
#define DSTATE 16
#define DCONV  4
#define DINNER 256
#define DTRANK 16
#define NBL    (B_SZ*LSEQ)        // 2048
#define NROWS  (2*DD*POLY*POLY)   // 25600
#define NSLOT  25                 // 1600/64 r-tiles per channel
#define NCH    32                 // scan chunks
#define LCH    32                 // chunk length
#define LDP    40                 // LDS row stride in shorts (R12-proven)

typedef __attribute__((ext_vector_type(8))) short bf16x8;
typedef __attribute__((ext_vector_type(8))) unsigned short us8;
typedef __attribute__((ext_vector_type(4))) unsigned short us4;
typedef __attribute__((ext_vector_type(4))) float f32x4;
typedef __attribute__((ext_vector_type(16))) float f32x16;

__device__ __forceinline__ float sigmoidf_(float x){ return 1.f/(1.f+__expf(-x)); }
__device__ __forceinline__ float softplusf_(float x){ return fmaxf(x,0.f) + log1pf(__expf(-fabsf(x))); }
__device__ __forceinline__ unsigned short f2bf(float f){
  unsigned int u = __float_as_uint(f);
  unsigned int r = (u + 0x7fffu + ((u>>16)&1u)) >> 16;
  return (unsigned short)r;
}

// ---- f32 -> bf16 (RNE), 8 elems/thread (used for Wb in overlay path) ----
__global__ void k_f2bf(const float* __restrict__ in, unsigned short* __restrict__ out, int n8){
  int i = blockIdx.x*blockDim.x + threadIdx.x;
  if (i>=n8) return;
  const float4* p = (const float4*)(in + (size_t)i*8);
  float4 a = p[0], b = p[1];
  us8 r;
  r[0]=f2bf(a.x); r[1]=f2bf(a.y); r[2]=f2bf(a.z); r[3]=f2bf(a.w);
  r[4]=f2bf(b.x); r[5]=f2bf(b.y); r[6]=f2bf(b.z); r[7]=f2bf(b.w);
  *(us8*)(out + (size_t)i*8) = r;
}

// ---- merged prologue: ipw/opw->bf16, wcomb, pmt, ctrl (+optional Wb) ----
#define IPW_N8 (NL*512*256/8)     // 32768
#define OPW_N8 (NL*256*256/8)     // 16384
#define PRE_B0 ((IPW_N8+OPW_N8)/256)      // 192
#define PRE_B1 (NL*288*256/256)           // 576
#define PRE_B2 (16*NBL/256)               // 128
#define PRE_B3 (NBL*256/256)              // 2048
#define PRE_B4 (NROWS*256/8/256)          // 3200
__global__ void k_prologue(const float* __restrict__ ipw, const float* __restrict__ opw,
                           const float* __restrict__ dtw, const float* __restrict__ xpw,
                           const float* __restrict__ x,   const float* __restrict__ y,
                           const float* __restrict__ cpw, const float* __restrict__ cpb,
                           const float* __restrict__ bnw,
                           unsigned short* __restrict__ ipwb,   // ipwb then opwb contiguous
                           unsigned short* __restrict__ wcomb,
                           float* __restrict__ pmt, float* __restrict__ u,
                           unsigned short* __restrict__ Wb){
  int bx = blockIdx.x; int tid = threadIdx.x;
  if (bx < PRE_B0){
    int i = bx*256 + tid;
    const float* src = (i < IPW_N8) ? (ipw + (size_t)i*8) : (opw + (size_t)(i-IPW_N8)*8);
    const float4* p = (const float4*)src;
    float4 a = p[0], b = p[1];
    us8 r;
    r[0]=f2bf(a.x); r[1]=f2bf(a.y); r[2]=f2bf(a.z); r[3]=f2bf(a.w);
    r[4]=f2bf(b.x); r[5]=f2bf(b.y); r[6]=f2bf(b.z); r[7]=f2bf(b.w);
    *(us8*)(ipwb + (size_t)i*8) = r;
  } else if (bx < PRE_B0+PRE_B1){
    int idx = (bx-PRE_B0)*256 + tid;
    int e = idx & 255; int row = (idx>>8) % 288; int l = idx / (288*256);
    float v;
    if (row < 256){
      float s=0.f;
      #pragma unroll
      for (int r=0;r<16;++r) s += dtw[((size_t)l*256+row)*16+r] * xpw[((size_t)l*48+r)*256+e];
      v = s;
    } else {
      v = xpw[((size_t)l*48 + (row-240))*256 + e];
    }
    wcomb[idx] = f2bf(v);
  } else if (bx < PRE_B0+PRE_B1+PRE_B2){
    int idx = (bx-PRE_B0-PRE_B1)*256 + tid;
    int m = idx & (NBL-1); int c = idx >> 11;
    float z;
    if (c < 8) z = x[(size_t)m*8 + c];
    else       z = y[(size_t)m*8 + (c-8)] - x[(size_t)m*8 + (c-8)];
    float p = 1.f;
    #pragma unroll
    for (int j=0;j<POLY;++j){ pmt[((size_t)c*POLY+j)*NBL + m] = p; p*=z; }
  } else if (bx < PRE_B0+PRE_B1+PRE_B2+PRE_B3){
    int idx = (bx-PRE_B0-PRE_B1-PRE_B2)*256 + tid;
    int e = idx & 255; int m = idx >> 8;
    int bb = m >> 10; int lm = m & 1023; int lo = 1023 - lm;
    const float* xp = x + ((size_t)bb*1024+lo)*8;
    const float* yp = y + ((size_t)bb*1024+lo)*8;
    const float* wr = cpw + (size_t)e*16;
    float acc = cpb[e];
    #pragma unroll
    for (int d=0; d<8; ++d) acc += (yp[d]-xp[d])*wr[d];
    #pragma unroll
    for (int d=0; d<8; ++d) acc += yp[d]*wr[8+d];
    u[idx] = acc;
  } else {
    int i = (bx-PRE_B0-PRE_B1-PRE_B2-PRE_B3)*256 + tid;
    const float4* p = (const float4*)(bnw + (size_t)i*8);
    float4 a = p[0], b = p[1];
    us8 r;
    r[0]=f2bf(a.x); r[1]=f2bf(a.y); r[2]=f2bf(a.z); r[3]=f2bf(a.w);
    r[4]=f2bf(b.x); r[5]=f2bf(b.y); r[6]=f2bf(b.z); r[7]=f2bf(b.w);
    *(us8*)(Wb + (size_t)i*8) = r;
  }
}

// ---- rmsnorm -> bf16 ----
__global__ void k_rms(const float* __restrict__ u, const float* __restrict__ nw,
                      unsigned short* __restrict__ rb){
  int m = blockIdx.x; int e = threadIdx.x;
  float v = u[(size_t)m*256 + e];
  float ss = v*v;
  #pragma unroll
  for (int off=32; off>0; off>>=1) ss += __shfl_down(ss, off);
  __shared__ float sred[4];
  __shared__ float srstd;
  int wid = e>>6; int lane = e&63;
  if (lane==0) sred[wid]=ss;
  __syncthreads();
  if (e==0){ float t = sred[0]+sred[1]+sred[2]+sred[3]; srstd = rsqrtf(t*(1.f/256.f) + 1e-5f); }
  __syncthreads();
  rb[(size_t)m*256+e] = f2bf(v * srstd * nw[e]);
}

// ---- generic MFMA NT GEMM (mamba-side), tile 64x64, 4 waves (2x2) of 32x32 ----
// Double-buffered LDS + single barrier + 2-deep prefetch.
// mode 0: C0[m*ldc+n] = acc
// mode 1: C0[m*ldc+n] += acc
// mode 2: n<256 -> C0[m*256+n] = softplus(acc+bias[n]); 256<=n<N -> C1[m*32+n-256] = acc
// mode 3: v = C0[m*ldc+n] + acc; write flipped: outsp[mf*256+n]=v, spb[mf*256+n]=bf16(v)
__global__ void __launch_bounds__(256)
gemm_bf(const unsigned short* __restrict__ A, const unsigned short* __restrict__ B,
        int N, int K, const float* __restrict__ bias,
        float* __restrict__ C0, float* __restrict__ C1, int ldc, int mode,
        float* __restrict__ outsp, unsigned short* __restrict__ spb){
  __shared__ __align__(16) unsigned short Asm[2][64*LDP];
  __shared__ __align__(16) unsigned short Bsm[2][64*LDP];
  int tid = threadIdx.x;
  int lane = tid & 63;
  int w = tid >> 6; int wr = w >> 1, wc = w & 1;
  int l15 = lane & 15, l4 = lane >> 4;
  int m0 = blockIdx.y*64, n0 = blockIdx.x*64;

  f32x4 acc[2][2];
  #pragma unroll
  for (int i=0;i<2;++i)
    #pragma unroll
    for (int j=0;j<2;++j){ acc[i][j][0]=0.f; acc[i][j][1]=0.f; acc[i][j][2]=0.f; acc[i][j][3]=0.f; }

  int row = tid>>2, c8 = tid&3;
  int bn = n0+row; int bValid = (bn < N);
  const unsigned short* aSrc = A + (size_t)(m0+row)*K + c8*8;
  const unsigned short* bSrc = B + (size_t)(bValid ? bn : 0)*K + c8*8;

  {
    us8 t0 = *(const us8*)(aSrc);
    us8 t1;
    if (bValid) t1 = *(const us8*)(bSrc);
    else        for (int z=0;z<8;++z) t1[z]=0;
    *(us8*)&Asm[0][row*LDP + c8*8] = t0;
    *(us8*)&Bsm[0][row*LDP + c8*8] = t1;
  }
  us8 pA = *(const us8*)(aSrc + 32);
  us8 pB;
  if (bValid) pB = *(const us8*)(bSrc + 32);
  else        for (int z=0;z<8;++z) pB[z]=0;
  __syncthreads();

  int cur = 0;
  for (int ks=0; ks<8; ++ks){
    us8 qA, qB;
    if (ks < 6){
      int k0nn = (ks+2)*32;
      qA = *(const us8*)(aSrc + k0nn);
      if (bValid) qB = *(const us8*)(bSrc + k0nn);
      else        for (int z=0;z<8;++z) qB[z]=0;
    }
    bf16x8 av[2], bv[2];
    #pragma unroll
    for (int i=0;i<2;++i) av[i] = *(bf16x8*)&Asm[cur][(wr*32+i*16+l15)*LDP + l4*8];
    #pragma unroll
    for (int j=0;j<2;++j) bv[j] = *(bf16x8*)&Bsm[cur][(wc*32+j*16+l15)*LDP + l4*8];
    __builtin_amdgcn_s_setprio(1);
    #pragma unroll
    for (int i=0;i<2;++i)
      #pragma unroll
      for (int j=0;j<2;++j)
        acc[i][j] = __builtin_amdgcn_mfma_f32_16x16x32_bf16(av[i], bv[j], acc[i][j], 0,0,0);
    __builtin_amdgcn_s_setprio(0);
    if (ks < 7){
      *(us8*)&Asm[cur^1][row*LDP + c8*8] = pA;
      *(us8*)&Bsm[cur^1][row*LDP + c8*8] = pB;
    }
    __syncthreads();
    cur ^= 1;
    if (ks < 6){ pA = qA; pB = qB; }
  }

  #pragma unroll
  for (int i=0;i<2;++i){
    #pragma unroll
    for (int j=0;j<2;++j){
      int n = n0 + wc*32 + j*16 + l15;
      #pragma unroll
      for (int q=0;q<4;++q){
        int m = m0 + wr*32 + i*16 + l4*4 + q;
        float v = acc[i][j][q];
        if (mode==0){
          C0[(size_t)m*ldc + n] = v;
        } else if (mode==1){
          C0[(size_t)m*ldc + n] += v;
        } else if (mode==2){
          if (n < 256) C0[(size_t)m*256 + n] = softplusf_(v + bias[n]);
          else if (n < N) C1[(size_t)m*32 + (n-256)] = v;
        } else {
          float t = C0[(size_t)m*ldc + n] + v;
          int bb = m >> 10; int lq = m & 1023;
          size_t mf = (size_t)bb*1024 + (1023-lq);
          outsp[mf*256 + n] = t;
          spb[mf*256 + n] = f2bf(t);
        }
      }
    }
  }
}

// ---- causal conv (K=4) + bias + silu; 4 channels/thread, outputs f32 + bf16 ----
__global__ void k_convsilu(const float* __restrict__ xz, const float* __restrict__ cw,
                           const float* __restrict__ cb, float* __restrict__ xc,
                           unsigned short* __restrict__ xcb){
  int idx = blockIdx.x*blockDim.x + threadIdx.x;  // m*64 + d4
  if (idx >= NBL*64) return;
  int d4 = (idx & 63) << 2; int m = idx >> 6;
  int bb = m>>10, l = m&1023;
  float4 w0 = *(const float4*)&cw[(d4+0)*4];
  float4 w1 = *(const float4*)&cw[(d4+1)*4];
  float4 w2 = *(const float4*)&cw[(d4+2)*4];
  float4 w3 = *(const float4*)&cw[(d4+3)*4];
  float4 cbv = *(const float4*)&cb[d4];
  float a0=cbv.x, a1=cbv.y, a2=cbv.z, a3=cbv.w;
  #pragma unroll
  for (int k=0;k<4;++k){
    int ls = l - 3 + k;
    if (ls >= 0){
      float4 v = *(const float4*)&xz[((size_t)(bb*1024+ls))*512 + d4];
      a0 += v.x * ((const float*)&w0)[k];
      a1 += v.y * ((const float*)&w1)[k];
      a2 += v.z * ((const float*)&w2)[k];
      a3 += v.w * ((const float*)&w3)[k];
    }
  }
  a0 = a0*sigmoidf_(a0); a1 = a1*sigmoidf_(a1);
  a2 = a2*sigmoidf_(a2); a3 = a3*sigmoidf_(a3);
  float4 o; o.x=a0; o.y=a1; o.z=a2; o.w=a3;
  *(float4*)&xc[(size_t)m*256 + d4] = o;
  us4 ob; ob[0]=f2bf(a0); ob[1]=f2bf(a1); ob[2]=f2bf(a2); ob[3]=f2bf(a3);
  *(us4*)&xcb[(size_t)m*256 + d4] = ob;
}

// ---- chunked scan pass 1 ----
__global__ void k_scan1(const float* __restrict__ delta, const float* __restrict__ bc,
                        const float* __restrict__ xc, const float* __restrict__ alog,
                        float* __restrict__ hend, float* __restrict__ Pc){
  int blk = blockIdx.x;              // bb*512 + ch*16 + dg
  int dg = blk & 15; int ch = (blk>>4) & (NCH-1); int bb = blk >> 9;
  int tid = threadIdx.x; int dl = tid>>4; int s = tid&15; int d = dg*16+dl;
  float A = -__expf(alog[(size_t)d*16+s]);
  float h = 0.f, p = 1.f;
  size_t base = (size_t)bb*1024 + ch*LCH;
  #pragma unroll 4
  for (int t=0;t<LCH;++t){
    size_t mb = base + t;
    float de  = delta[mb*256+d];
    float Bv  = bc[mb*32+s];
    float xcv = xc[mb*256+d];
    float a = __expf(de*A);
    h = a*h + de*Bv*xcv;
    p *= a;
  }
  size_t o = (((size_t)bb*NCH+ch)*256+d)*16+s;
  hend[o]=h; Pc[o]=p;
}

// ---- pass 2: chunk-level recurrence ----
__global__ void k_scan2(const float* __restrict__ hend, const float* __restrict__ Pc,
                        float* __restrict__ Hinit){
  int idx = blockIdx.x*blockDim.x + threadIdx.x;  // bb*4096 + d*16+s
  if (idx >= B_SZ*256*16) return;
  int bb = idx >> 12; int ds = idx & 4095;
  float H = 0.f;
  #pragma unroll
  for (int ch=0; ch<NCH; ++ch){
    size_t o = ((size_t)bb*NCH+ch)*4096 + ds;
    Hinit[o] = H;
    H = Pc[o]*H + hend[o];
  }
}

// ---- pass 3: re-run chunks from correct init, emit gated y (bf16) ----
__global__ void k_scan3(const float* __restrict__ delta, const float* __restrict__ bc,
                        const float* __restrict__ xc, const float* __restrict__ xz,
                        const float* __restrict__ alog, const float* __restrict__ dskip,
                        const float* __restrict__ Hinit, unsigned short* __restrict__ yvb){
  int blk = blockIdx.x;
  int dg = blk & 15; int ch = (blk>>4) & (NCH-1); int bb = blk >> 9;
  int tid = threadIdx.x; int dl = tid>>4; int s = tid&15; int d = dg*16+dl;
  float A = -__expf(alog[(size_t)d*16+s]);
  float dsk = dskip[d];
  float h = Hinit[(((size_t)bb*NCH+ch)*256+d)*16+s];
  size_t base = (size_t)bb*1024 + ch*LCH;
  #pragma unroll 2
  for (int t=0;t<LCH;++t){
    size_t mb = base + t;
    float de  = delta[mb*256+d];
    float Bv  = bc[mb*32+s];
    float Cv  = bc[mb*32+16+s];
    float xcv = xc[mb*256+d];
    float a = __expf(de*A);
    h = a*h + de*Bv*xcv;
    float yval = h*Cv;
    yval += __shfl_xor(yval,1);
    yval += __shfl_xor(yval,2);
    yval += __shfl_xor(yval,4);
    yval += __shfl_xor(yval,8);
    if (s==0){
      float zg = xz[mb*512+256+d];
      yvb[mb*256+d] = f2bf((yval + dsk*xcv) * zg * sigmoidf_(zg));
    }
  }
}

// ---- fused b_net MFMA GEMM + bilinear pm contraction -> partials ----
// Tile: BM=128, BN=64, BK=32, K=256. 4 waves in 2x2, wave 64x32 via 32x32x16 MFMA
// (2 frags x 2 k-halves per K-step). Double-buffered LDS, single barrier, 2-deep
// prefetch, setprio. C/D layout: col=lane&31, row=(reg&3)+8*(reg>>2)+4*(lane>>5).
// part layout: [c][slot][m].
__global__ void __launch_bounds__(256)
k_bnet_mfma(const unsigned short* __restrict__ spb, const unsigned short* __restrict__ Wb,
            const float* __restrict__ bnb, const float* __restrict__ pmt,
            float* __restrict__ part){
  __shared__ __align__(16) unsigned short Asm[2][128*LDP];  // 2 x 10KB
  __shared__ __align__(16) unsigned short Bsm[2][64*LDP];   // 2 x 5KB
  __shared__ float red[2][128];

  int tid = threadIdx.x;
  int lane = tid & 63;
  int w = tid >> 6;                 // 0..3
  int wr = w >> 1, wc = w & 1;      // wr 0..1, wc 0..1
  int col = lane & 31, l5 = lane >> 5;
  int bx = blockIdx.x;              // 0..399
  int m0 = blockIdx.y*128;
  int n0 = bx*64;

  int aRow0 = (tid)>>2,        aC0 = (tid)&3;
  int aRow1 = (tid+256)>>2,    aC1 = (tid+256)&3;
  int bRow  = tid>>2,          bC  = tid&3;
  const unsigned short* aSrc0 = spb + ((size_t)(m0+aRow0))*256 + aC0*8;
  const unsigned short* aSrc1 = spb + ((size_t)(m0+aRow1))*256 + aC1*8;
  const unsigned short* bSrc  = Wb  + ((size_t)(n0+bRow ))*256 + bC*8;

  f32x16 acc[2];
  #pragma unroll
  for (int i=0;i<2;++i)
    #pragma unroll
    for (int r=0;r<16;++r) acc[i][r] = 0.f;

  // stage tile 0 into buf 0; then issue tile-1 loads (pending regs)
  {
    us8 t0 = *(const us8*)(aSrc0);
    us8 t1 = *(const us8*)(aSrc1);
    us8 t2 = *(const us8*)(bSrc);
    *(us8*)&Asm[0][aRow0*LDP + aC0*8] = t0;
    *(us8*)&Asm[0][aRow1*LDP + aC1*8] = t1;
    *(us8*)&Bsm[0][bRow*LDP + bC*8]   = t2;
  }
  us8 pA0 = *(const us8*)(aSrc0 + 32);
  us8 pA1 = *(const us8*)(aSrc1 + 32);
  us8 pB  = *(const us8*)(bSrc  + 32);
  __syncthreads();

  int cur = 0;
  for (int ks=0; ks<8; ++ks){
    us8 qA0, qA1, qB;
    if (ks < 6){
      int k0nn = (ks+2)*32;
      qA0 = *(const us8*)(aSrc0 + k0nn);
      qA1 = *(const us8*)(aSrc1 + k0nn);
      qB  = *(const us8*)(bSrc  + k0nn);
    }
    // operands: A rows wr*64+i*32+col, k = kh*16 + l5*8 (+0..7)
    bf16x8 aA[2][2], bB[2];
    #pragma unroll
    for (int i=0;i<2;++i)
      #pragma unroll
      for (int kh=0;kh<2;++kh)
        aA[i][kh] = *(bf16x8*)&Asm[cur][(wr*64 + i*32 + col)*LDP + kh*16 + l5*8];
    #pragma unroll
    for (int kh=0;kh<2;++kh)
      bB[kh] = *(bf16x8*)&Bsm[cur][(wc*32 + col)*LDP + kh*16 + l5*8];
    __builtin_amdgcn_s_setprio(1);
    #pragma unroll
    for (int kh=0;kh<2;++kh)
      #pragma unroll
      for (int i=0;i<2;++i)
        acc[i] = __builtin_amdgcn_mfma_f32_32x32x16_bf16(aA[i][kh], bB[kh], acc[i], 0,0,0);
    __builtin_amdgcn_s_setprio(0);
    if (ks < 7){
      *(us8*)&Asm[cur^1][aRow0*LDP + aC0*8] = pA0;
      *(us8*)&Asm[cur^1][aRow1*LDP + aC1*8] = pA1;
      *(us8*)&Bsm[cur^1][bRow*LDP + bC*8]   = pB;
    }
    __syncthreads();
    cur ^= 1;
    if (ks < 6){ pA0 = qA0; pA1 = qA1; pB = qB; }
  }

  // epilogue: bilinear pmt contraction + 32-lane reduce
  int c = bx/25, slot = bx%25;
  int nl = wc*32 + col;
  int rem = slot*64 + nl;
  float bnbv = bnb[n0 + nl];
  int kk = rem/40, jj = rem%40;
  const float* pc  = pmt + (size_t)c*POLY*NBL;
  const float* pcf = pmt + (size_t)(15-c)*POLY*NBL;
  #pragma unroll
  for (int i=0;i<2;++i){
    #pragma unroll
    for (int g=0;g<4;++g){
      int mb = m0 + wr*64 + i*32 + 8*g + 4*l5;   // rows mb..mb+3 (reg&3)
      f32x4 pk = *(const f32x4*)&pc [(size_t)kk*NBL + mb];
      f32x4 pj = *(const f32x4*)&pcf[(size_t)jj*NBL + mb];
      f32x4 s;
      #pragma unroll
      for (int q=0;q<4;++q) s[q] = (acc[i][g*4+q] + bnbv) * pk[q] * pj[q];
      #pragma unroll
      for (int q=0;q<4;++q){
        float t = s[q];
        t += __shfl_xor(t,1); t += __shfl_xor(t,2);
        t += __shfl_xor(t,4); t += __shfl_xor(t,8);
        t += __shfl_xor(t,16);
        if (col==0) red[wc][wr*64 + i*32 + 8*g + 4*l5 + q] = t;
      }
    }
  }
  __syncthreads();
  if (tid < 128){
    float v = red[0][tid] + red[1][tid];
    part[((size_t)(c*NSLOT + slot))*NBL + m0 + tid] = v;   // coalesced (m inner)
  }
}

// ---- final zdot: sum 25 partials, drop l=0 (coalesced reads) ----
__global__ void k_final(const float* __restrict__ part, float* __restrict__ out){
  int j = blockIdx.x*blockDim.x+threadIdx.x;   // c*2046 + r
  if (j >= 16*2046) return;
  int c = j / 2046; int r = j % 2046;
  int bb = r / 1023; int l = r % 1023 + 1;
  size_t m = (size_t)bb*1024 + l;
  float s = 0.f;
  #pragma unroll
  for (int q=0;q<NSLOT;++q) s += part[((size_t)(c*NSLOT + q))*NBL + m];
  out[((size_t)(bb*1023 + (l-1)))*16 + c] = s;
}

extern "C" void kernel_launch(void* const* d_in, const int* in_sizes, int n_in,
                              void* d_out, int out_size, void* d_ws, size_t ws_size,
                              hipStream_t stream) {
  const float* x    = (const float*)d_in[0];
  const float* y    = (const float*)d_in[1];
  const float* cpw  = (const float*)d_in[2];
  const float* cpb  = (const float*)d_in[3];
  const float* nw   = (const float*)d_in[4];
  const float* ipw  = (const float*)d_in[5];
  const float* cvw  = (const float*)d_in[6];
  const float* cvb  = (const float*)d_in[7];
  const float* xpw  = (const float*)d_in[8];
  const float* dtw  = (const float*)d_in[9];
  const float* dtb  = (const float*)d_in[10];
  const float* alog = (const float*)d_in[11];
  const float* dsk  = (const float*)d_in[12];
  const float* opw  = (const float*)d_in[13];
  const float* bnw  = (const float*)d_in[14];
  const float* bnb  = (const float*)d_in[15];

  float* out      = (float*)d_out;
  float* out_zdot = out;                 // 2*1023*16
  float* out_sp   = out + 32736;         // 2*1024*256

  float* ws = (float*)d_ws;
  size_t off = 0;
  // --- overlay region (dead after last out_proj; Wb overlays it in fallback path) ---
  float* u     = ws + off; off += (size_t)NBL*256;            //   524288
  unsigned short* rb = (unsigned short*)(ws + off); off += (size_t)NBL*256/2;   // 262144
  float* xz    = ws + off; off += (size_t)NBL*512;            // 1048576
  float* xc    = ws + off; off += (size_t)NBL*256;            //  524288
  unsigned short* xcb = (unsigned short*)(ws + off); off += (size_t)NBL*256/2;  // 262144
  float* delta = ws + off; off += (size_t)NBL*256;            //  524288
  float* bcm   = ws + off; off += (size_t)NBL*32;             //   65536
  unsigned short* yvb = (unsigned short*)(ws + off); off += (size_t)NBL*256/2;  // 262144
  // overlay total = 3,473,408 floats >= Wb's 3,276,800 -> overlay is safe
  // --- persistent region ---
  float* pmt   = ws + off; off += (size_t)NBL*16*POLY;
  float* part  = ws + off; off += (size_t)NSLOT*NBL*16;
  float* hend  = ws + off; off += (size_t)B_SZ*NCH*256*16;
  float* Pc    = ws + off; off += (size_t)B_SZ*NCH*256*16;
  float* Hinit = ws + off; off += (size_t)B_SZ*NCH*256*16;
  unsigned short* spb  = (unsigned short*)(ws + off); off += (size_t)NBL*256/2;
  // ipwb+opwb hold (IPW_N8+OPW_N8)*8 bf16 = (IPW_N8+OPW_N8)*4 floats
  unsigned short* ipwb = (unsigned short*)(ws + off); off += (size_t)(IPW_N8+OPW_N8)*4;
  unsigned short* wcomb= (unsigned short*)(ws + off); off += (size_t)NL*288*256/2;

  // Wb placement: separate region if ws permits (convert early, off critical path),
  // else overlay the mamba temporaries (convert after the mamba loop). Deterministic.
  int wbEarly = ((off + (size_t)NROWS*256/2)*sizeof(float) <= ws_size) ? 1 : 0;
  unsigned short* Wb = wbEarly ? (unsigned short*)(ws + off) : (unsigned short*)ws;

  unsigned short* opwb = ipwb + (size_t)IPW_N8*8;   // opwb contiguous after ipwb

  int preBlocks = PRE_B0+PRE_B1+PRE_B2+PRE_B3 + (wbEarly ? PRE_B4 : 0);
  k_prologue<<<preBlocks, 256, 0, stream>>>(ipw, opw, dtw, xpw, x, y, cpw, cpb, bnw,
                                            ipwb, wcomb, pmt, u, Wb);

  for (int i=0;i<NL;++i){
    k_rms<<<NBL, 256, 0, stream>>>(u, nw + i*256, rb);
    gemm_bf<<<dim3(8,32), 256, 0, stream>>>(rb, ipwb + (size_t)i*512*256, 512, 256,
                                            nullptr, xz, nullptr, 512, 0, nullptr, nullptr);
    k_convsilu<<<(NBL*64+255)/256, 256, 0, stream>>>(xz, cvw + i*256*4, cvb + i*256, xc, xcb);
    gemm_bf<<<dim3(5,32), 256, 0, stream>>>(xcb, wcomb + (size_t)i*288*256, 288, 256,
                                            dtb + i*256, delta, bcm, 256, 2, nullptr, nullptr);
    k_scan1<<<B_SZ*NCH*16, 256, 0, stream>>>(delta, bcm, xc, alog + (size_t)i*256*16, hend, Pc);
    k_scan2<<<(B_SZ*256*16+255)/256, 256, 0, stream>>>(hend, Pc, Hinit);
    k_scan3<<<B_SZ*NCH*16, 256, 0, stream>>>(delta, bcm, xc, xz, alog + (size_t)i*256*16,
                                             dsk + i*256, Hinit, yvb);
    if (i < NL-1){
      gemm_bf<<<dim3(4,32), 256, 0, stream>>>(yvb, opwb + (size_t)i*256*256, 256, 256,
                                              nullptr, u, nullptr, 256, 1, nullptr, nullptr);
    } else {
      // fused: residual + flip + state_pred store + bf16 copy for b_net
      gemm_bf<<<dim3(4,32), 256, 0, stream>>>(yvb, opwb + (size_t)i*256*256, 256, 256,
                                              nullptr, u, nullptr, 256, 3, out_sp, spb);
    }
  }

  if (!wbEarly){
    // overlay path: u..yvb now dead -> convert bnw into the overlay
    k_f2bf<<<(NROWS*256/8 + 255)/256, 256, 0, stream>>>(bnw, Wb, NROWS*256/8);
  }
  k_bnet_mfma<<<dim3(NROWS/64, NBL/128), 256, 0, stream>>>(spb, Wb, bnb, pmt, part);
  k_final<<<(16*2046+255)/256, 256, 0, stream>>>(part, out_zdot);
}

// Round 20
// 211.735 us; speedup vs baseline: 1.1079x; 1.1079x over previous
//
#include <hip/hip_runtime.h>
#include <hip/hip_bf16.h>

#define B_SZ   2
#define LSEQ   1024
#define DD     8
#define DCTRL  256
#define POLY   40
#define NL     2
#define DSTATE 16
#define DCONV  4
#define DINNER 256
#define DTRANK 16
#define NBL    (B_SZ*LSEQ)        // 2048
#define NROWS  (2*DD*POLY*POLY)   // 25600
#define NSLOT  25                 // 1600/64 r-tiles per channel
#define NCH    32                 // scan chunks
#define LCH    32                 // chunk length
#define LDP    40                 // LDS row stride in shorts (R12-proven)

typedef __attribute__((ext_vector_type(8))) short bf16x8;
typedef __attribute__((ext_vector_type(8))) unsigned short us8;
typedef __attribute__((ext_vector_type(4))) unsigned short us4;
typedef __attribute__((ext_vector_type(4))) float f32x4;

__device__ __forceinline__ float sigmoidf_(float x){ return 1.f/(1.f+__expf(-x)); }
__device__ __forceinline__ float softplusf_(float x){ return fmaxf(x,0.f) + log1pf(__expf(-fabsf(x))); }
__device__ __forceinline__ unsigned short f2bf(float f){
  unsigned int u = __float_as_uint(f);
  unsigned int r = (u + 0x7fffu + ((u>>16)&1u)) >> 16;
  return (unsigned short)r;
}

// ---- f32 -> bf16 (RNE), 8 elems/thread (used for Wb in overlay path) ----
__global__ void k_f2bf(const float* __restrict__ in, unsigned short* __restrict__ out, int n8){
  int i = blockIdx.x*blockDim.x + threadIdx.x;
  if (i>=n8) return;
  const float4* p = (const float4*)(in + (size_t)i*8);
  float4 a = p[0], b = p[1];
  us8 r;
  r[0]=f2bf(a.x); r[1]=f2bf(a.y); r[2]=f2bf(a.z); r[3]=f2bf(a.w);
  r[4]=f2bf(b.x); r[5]=f2bf(b.y); r[6]=f2bf(b.z); r[7]=f2bf(b.w);
  *(us8*)(out + (size_t)i*8) = r;
}

// ---- merged prologue: ipw/opw->bf16, wcomb, pmt, ctrl (+optional Wb) ----
#define IPW_N8 (NL*512*256/8)     // 32768
#define OPW_N8 (NL*256*256/8)     // 16384
#define PRE_B0 ((IPW_N8+OPW_N8)/256)      // 192
#define PRE_B1 (NL*288*256/256)           // 576
#define PRE_B2 (16*NBL/256)               // 128
#define PRE_B3 (NBL*256/256)              // 2048
#define PRE_B4 (NROWS*256/8/256)          // 3200
__global__ void k_prologue(const float* __restrict__ ipw, const float* __restrict__ opw,
                           const float* __restrict__ dtw, const float* __restrict__ xpw,
                           const float* __restrict__ x,   const float* __restrict__ y,
                           const float* __restrict__ cpw, const float* __restrict__ cpb,
                           const float* __restrict__ bnw,
                           unsigned short* __restrict__ ipwb,   // ipwb then opwb contiguous
                           unsigned short* __restrict__ wcomb,
                           float* __restrict__ pmt, float* __restrict__ u,
                           unsigned short* __restrict__ Wb){
  int bx = blockIdx.x; int tid = threadIdx.x;
  if (bx < PRE_B0){
    int i = bx*256 + tid;
    const float* src = (i < IPW_N8) ? (ipw + (size_t)i*8) : (opw + (size_t)(i-IPW_N8)*8);
    const float4* p = (const float4*)src;
    float4 a = p[0], b = p[1];
    us8 r;
    r[0]=f2bf(a.x); r[1]=f2bf(a.y); r[2]=f2bf(a.z); r[3]=f2bf(a.w);
    r[4]=f2bf(b.x); r[5]=f2bf(b.y); r[6]=f2bf(b.z); r[7]=f2bf(b.w);
    *(us8*)(ipwb + (size_t)i*8) = r;
  } else if (bx < PRE_B0+PRE_B1){
    int idx = (bx-PRE_B0)*256 + tid;
    int e = idx & 255; int row = (idx>>8) % 288; int l = idx / (288*256);
    float v;
    if (row < 256){
      float s=0.f;
      #pragma unroll
      for (int r=0;r<16;++r) s += dtw[((size_t)l*256+row)*16+r] * xpw[((size_t)l*48+r)*256+e];
      v = s;
    } else {
      v = xpw[((size_t)l*48 + (row-240))*256 + e];
    }
    wcomb[idx] = f2bf(v);
  } else if (bx < PRE_B0+PRE_B1+PRE_B2){
    int idx = (bx-PRE_B0-PRE_B1)*256 + tid;
    int m = idx & (NBL-1); int c = idx >> 11;
    float z;
    if (c < 8) z = x[(size_t)m*8 + c];
    else       z = y[(size_t)m*8 + (c-8)] - x[(size_t)m*8 + (c-8)];
    float p = 1.f;
    #pragma unroll
    for (int j=0;j<POLY;++j){ pmt[((size_t)c*POLY+j)*NBL + m] = p; p*=z; }
  } else if (bx < PRE_B0+PRE_B1+PRE_B2+PRE_B3){
    int idx = (bx-PRE_B0-PRE_B1-PRE_B2)*256 + tid;
    int e = idx & 255; int m = idx >> 8;
    int bb = m >> 10; int lm = m & 1023; int lo = 1023 - lm;
    const float* xp = x + ((size_t)bb*1024+lo)*8;
    const float* yp = y + ((size_t)bb*1024+lo)*8;
    const float* wr = cpw + (size_t)e*16;
    float acc = cpb[e];
    #pragma unroll
    for (int d=0; d<8; ++d) acc += (yp[d]-xp[d])*wr[d];
    #pragma unroll
    for (int d=0; d<8; ++d) acc += yp[d]*wr[8+d];
    u[idx] = acc;
  } else {
    int i = (bx-PRE_B0-PRE_B1-PRE_B2-PRE_B3)*256 + tid;
    const float4* p = (const float4*)(bnw + (size_t)i*8);
    float4 a = p[0], b = p[1];
    us8 r;
    r[0]=f2bf(a.x); r[1]=f2bf(a.y); r[2]=f2bf(a.z); r[3]=f2bf(a.w);
    r[4]=f2bf(b.x); r[5]=f2bf(b.y); r[6]=f2bf(b.z); r[7]=f2bf(b.w);
    *(us8*)(Wb + (size_t)i*8) = r;
  }
}

// ---- rmsnorm -> bf16 ----
__global__ void k_rms(const float* __restrict__ u, const float* __restrict__ nw,
                      unsigned short* __restrict__ rb){
  int m = blockIdx.x; int e = threadIdx.x;
  float v = u[(size_t)m*256 + e];
  float ss = v*v;
  #pragma unroll
  for (int off=32; off>0; off>>=1) ss += __shfl_down(ss, off);
  __shared__ float sred[4];
  __shared__ float srstd;
  int wid = e>>6; int lane = e&63;
  if (lane==0) sred[wid]=ss;
  __syncthreads();
  if (e==0){ float t = sred[0]+sred[1]+sred[2]+sred[3]; srstd = rsqrtf(t*(1.f/256.f) + 1e-5f); }
  __syncthreads();
  rb[(size_t)m*256+e] = f2bf(v * srstd * nw[e]);
}

// ---- generic MFMA NT GEMM (mamba-side), tile 64x64, 4 waves (2x2) of 32x32 ----
// Double-buffered LDS + single barrier + 2-deep prefetch (k_bnet-proven structure).
// All uses have K=256 (8 K-steps).
// mode 0: C0[m*ldc+n] = acc
// mode 1: C0[m*ldc+n] += acc
// mode 2: n<256 -> C0[m*256+n] = softplus(acc+bias[n]); 256<=n<N -> C1[m*32+n-256] = acc
// mode 3: v = C0[m*ldc+n] + acc; write flipped: outsp[mf*256+n]=v, spb[mf*256+n]=bf16(v)
__global__ void __launch_bounds__(256)
gemm_bf(const unsigned short* __restrict__ A, const unsigned short* __restrict__ B,
        int N, int K, const float* __restrict__ bias,
        float* __restrict__ C0, float* __restrict__ C1, int ldc, int mode,
        float* __restrict__ outsp, unsigned short* __restrict__ spb){
  __shared__ __align__(16) unsigned short Asm[2][64*LDP];
  __shared__ __align__(16) unsigned short Bsm[2][64*LDP];
  int tid = threadIdx.x;
  int lane = tid & 63;
  int w = tid >> 6; int wr = w >> 1, wc = w & 1;
  int l15 = lane & 15, l4 = lane >> 4;
  int m0 = blockIdx.y*64, n0 = blockIdx.x*64;

  f32x4 acc[2][2];
  #pragma unroll
  for (int i=0;i<2;++i)
    #pragma unroll
    for (int j=0;j<2;++j){ acc[i][j][0]=0.f; acc[i][j][1]=0.f; acc[i][j][2]=0.f; acc[i][j][3]=0.f; }

  int row = tid>>2, c8 = tid&3;
  int bn = n0+row; int bValid = (bn < N);
  const unsigned short* aSrc = A + (size_t)(m0+row)*K + c8*8;
  const unsigned short* bSrc = B + (size_t)(bValid ? bn : 0)*K + c8*8;

  // stage tile 0 into buf 0
  {
    us8 t0 = *(const us8*)(aSrc);
    us8 t1;
    if (bValid) t1 = *(const us8*)(bSrc);
    else        for (int z=0;z<8;++z) t1[z]=0;
    *(us8*)&Asm[0][row*LDP + c8*8] = t0;
    *(us8*)&Bsm[0][row*LDP + c8*8] = t1;
  }
  // pending tile 1
  us8 pA = *(const us8*)(aSrc + 32);
  us8 pB;
  if (bValid) pB = *(const us8*)(bSrc + 32);
  else        for (int z=0;z<8;++z) pB[z]=0;
  __syncthreads();

  int cur = 0;
  for (int ks=0; ks<8; ++ks){
    us8 qA, qB;
    if (ks < 6){
      int k0nn = (ks+2)*32;
      qA = *(const us8*)(aSrc + k0nn);
      if (bValid) qB = *(const us8*)(bSrc + k0nn);
      else        for (int z=0;z<8;++z) qB[z]=0;
    }
    bf16x8 av[2], bv[2];
    #pragma unroll
    for (int i=0;i<2;++i) av[i] = *(bf16x8*)&Asm[cur][(wr*32+i*16+l15)*LDP + l4*8];
    #pragma unroll
    for (int j=0;j<2;++j) bv[j] = *(bf16x8*)&Bsm[cur][(wc*32+j*16+l15)*LDP + l4*8];
    __builtin_amdgcn_s_setprio(1);
    #pragma unroll
    for (int i=0;i<2;++i)
      #pragma unroll
      for (int j=0;j<2;++j)
        acc[i][j] = __builtin_amdgcn_mfma_f32_16x16x32_bf16(av[i], bv[j], acc[i][j], 0,0,0);
    __builtin_amdgcn_s_setprio(0);
    if (ks < 7){
      *(us8*)&Asm[cur^1][row*LDP + c8*8] = pA;
      *(us8*)&Bsm[cur^1][row*LDP + c8*8] = pB;
    }
    __syncthreads();
    cur ^= 1;
    if (ks < 6){ pA = qA; pB = qB; }
  }

  #pragma unroll
  for (int i=0;i<2;++i){
    #pragma unroll
    for (int j=0;j<2;++j){
      int n = n0 + wc*32 + j*16 + l15;
      #pragma unroll
      for (int q=0;q<4;++q){
        int m = m0 + wr*32 + i*16 + l4*4 + q;
        float v = acc[i][j][q];
        if (mode==0){
          C0[(size_t)m*ldc + n] = v;
        } else if (mode==1){
          C0[(size_t)m*ldc + n] += v;
        } else if (mode==2){
          if (n < 256) C0[(size_t)m*256 + n] = softplusf_(v + bias[n]);
          else if (n < N) C1[(size_t)m*32 + (n-256)] = v;
        } else {
          // mode 3: residual add + flipped store (state_pred) + bf16 copy
          float t = C0[(size_t)m*ldc + n] + v;
          int bb = m >> 10; int lq = m & 1023;
          size_t mf = (size_t)bb*1024 + (1023-lq);
          outsp[mf*256 + n] = t;
          spb[mf*256 + n] = f2bf(t);
        }
      }
    }
  }
}

// ---- causal conv (K=4) + bias + silu; 4 channels/thread, outputs f32 + bf16 ----
__global__ void k_convsilu(const float* __restrict__ xz, const float* __restrict__ cw,
                           const float* __restrict__ cb, float* __restrict__ xc,
                           unsigned short* __restrict__ xcb){
  int idx = blockIdx.x*blockDim.x + threadIdx.x;  // m*64 + d4
  if (idx >= NBL*64) return;
  int d4 = (idx & 63) << 2; int m = idx >> 6;
  int bb = m>>10, l = m&1023;
  float4 w0 = *(const float4*)&cw[(d4+0)*4];
  float4 w1 = *(const float4*)&cw[(d4+1)*4];
  float4 w2 = *(const float4*)&cw[(d4+2)*4];
  float4 w3 = *(const float4*)&cw[(d4+3)*4];
  float4 cbv = *(const float4*)&cb[d4];
  float a0=cbv.x, a1=cbv.y, a2=cbv.z, a3=cbv.w;
  #pragma unroll
  for (int k=0;k<4;++k){
    int ls = l - 3 + k;
    if (ls >= 0){
      float4 v = *(const float4*)&xz[((size_t)(bb*1024+ls))*512 + d4];
      a0 += v.x * ((const float*)&w0)[k];
      a1 += v.y * ((const float*)&w1)[k];
      a2 += v.z * ((const float*)&w2)[k];
      a3 += v.w * ((const float*)&w3)[k];
    }
  }
  a0 = a0*sigmoidf_(a0); a1 = a1*sigmoidf_(a1);
  a2 = a2*sigmoidf_(a2); a3 = a3*sigmoidf_(a3);
  float4 o; o.x=a0; o.y=a1; o.z=a2; o.w=a3;
  *(float4*)&xc[(size_t)m*256 + d4] = o;
  us4 ob; ob[0]=f2bf(a0); ob[1]=f2bf(a1); ob[2]=f2bf(a2); ob[3]=f2bf(a3);
  *(us4*)&xcb[(size_t)m*256 + d4] = ob;
}

// ---- chunked scan pass 1 ----
__global__ void k_scan1(const float* __restrict__ delta, const float* __restrict__ bc,
                        const float* __restrict__ xc, const float* __restrict__ alog,
                        float* __restrict__ hend, float* __restrict__ Pc){
  int blk = blockIdx.x;              // bb*512 + ch*16 + dg
  int dg = blk & 15; int ch = (blk>>4) & (NCH-1); int bb = blk >> 9;
  int tid = threadIdx.x; int dl = tid>>4; int s = tid&15; int d = dg*16+dl;
  float A = -__expf(alog[(size_t)d*16+s]);
  float h = 0.f, p = 1.f;
  size_t base = (size_t)bb*1024 + ch*LCH;
  #pragma unroll 4
  for (int t=0;t<LCH;++t){
    size_t mb = base + t;
    float de  = delta[mb*256+d];
    float Bv  = bc[mb*32+s];
    float xcv = xc[mb*256+d];
    float a = __expf(de*A);
    h = a*h + de*Bv*xcv;
    p *= a;
  }
  size_t o = (((size_t)bb*NCH+ch)*256+d)*16+s;
  hend[o]=h; Pc[o]=p;
}

// ---- pass 2: chunk-level recurrence ----
__global__ void k_scan2(const float* __restrict__ hend, const float* __restrict__ Pc,
                        float* __restrict__ Hinit){
  int idx = blockIdx.x*blockDim.x + threadIdx.x;  // bb*4096 + d*16+s
  if (idx >= B_SZ*256*16) return;
  int bb = idx >> 12; int ds = idx & 4095;
  float H = 0.f;
  #pragma unroll
  for (int ch=0; ch<NCH; ++ch){
    size_t o = ((size_t)bb*NCH+ch)*4096 + ds;
    Hinit[o] = H;
    H = Pc[o]*H + hend[o];
  }
}

// ---- pass 3: re-run chunks from correct init, emit gated y (bf16) ----
__global__ void k_scan3(const float* __restrict__ delta, const float* __restrict__ bc,
                        const float* __restrict__ xc, const float* __restrict__ xz,
                        const float* __restrict__ alog, const float* __restrict__ dskip,
                        const float* __restrict__ Hinit, unsigned short* __restrict__ yvb){
  int blk = blockIdx.x;
  int dg = blk & 15; int ch = (blk>>4) & (NCH-1); int bb = blk >> 9;
  int tid = threadIdx.x; int dl = tid>>4; int s = tid&15; int d = dg*16+dl;
  float A = -__expf(alog[(size_t)d*16+s]);
  float dsk = dskip[d];
  float h = Hinit[(((size_t)bb*NCH+ch)*256+d)*16+s];
  size_t base = (size_t)bb*1024 + ch*LCH;
  #pragma unroll 2
  for (int t=0;t<LCH;++t){
    size_t mb = base + t;
    float de  = delta[mb*256+d];
    float Bv  = bc[mb*32+s];
    float Cv  = bc[mb*32+16+s];
    float xcv = xc[mb*256+d];
    float a = __expf(de*A);
    h = a*h + de*Bv*xcv;
    float yval = h*Cv;
    yval += __shfl_xor(yval,1);
    yval += __shfl_xor(yval,2);
    yval += __shfl_xor(yval,4);
    yval += __shfl_xor(yval,8);
    if (s==0){
      float zg = xz[mb*512+256+d];
      yvb[mb*256+d] = f2bf((yval + dsk*xcv) * zg * sigmoidf_(zg));
    }
  }
}

// ---- fused b_net MFMA GEMM + bilinear pm contraction -> partials ----
// Tile: BM=128, BN=64, BK=32, K=256. 4 waves in 2x2, wave 64x32.
// Double-buffered LDS, single barrier per K-step, 2-deep global prefetch; setprio on MFMA.
// part layout: [c][slot][m].
__global__ void __launch_bounds__(256)
k_bnet_mfma(const unsigned short* __restrict__ spb, const unsigned short* __restrict__ Wb,
            const float* __restrict__ bnb, const float* __restrict__ pmt,
            float* __restrict__ part){
  __shared__ __align__(16) unsigned short Asm[2][128*LDP];  // 2 x 10KB
  __shared__ __align__(16) unsigned short Bsm[2][64*LDP];   // 2 x 5KB
  __shared__ float red[2][128];

  int tid = threadIdx.x;
  int lane = tid & 63;
  int w = tid >> 6;                 // 0..3
  int wr = w >> 1, wc = w & 1;      // wr 0..1, wc 0..1
  int l15 = lane & 15, l4 = lane >> 4;
  int bx = blockIdx.x;              // 0..399
  int m0 = blockIdx.y*128;
  int n0 = bx*64;

  int aRow0 = (tid)>>2,        aC0 = (tid)&3;
  int aRow1 = (tid+256)>>2,    aC1 = (tid+256)&3;
  int bRow  = tid>>2,          bC  = tid&3;
  const unsigned short* aSrc0 = spb + ((size_t)(m0+aRow0))*256 + aC0*8;
  const unsigned short* aSrc1 = spb + ((size_t)(m0+aRow1))*256 + aC1*8;
  const unsigned short* bSrc  = Wb  + ((size_t)(n0+bRow ))*256 + bC*8;

  f32x4 acc[4][2];
  #pragma unroll
  for (int i=0;i<4;++i)
    #pragma unroll
    for (int j=0;j<2;++j){ acc[i][j][0]=0.f; acc[i][j][1]=0.f; acc[i][j][2]=0.f; acc[i][j][3]=0.f; }

  // stage tile 0 into buf 0; then issue tile-1 loads (pending regs)
  {
    us8 t0 = *(const us8*)(aSrc0);
    us8 t1 = *(const us8*)(aSrc1);
    us8 t2 = *(const us8*)(bSrc);
    *(us8*)&Asm[0][aRow0*LDP + aC0*8] = t0;
    *(us8*)&Asm[0][aRow1*LDP + aC1*8] = t1;
    *(us8*)&Bsm[0][bRow*LDP + bC*8]   = t2;
  }
  us8 pA0 = *(const us8*)(aSrc0 + 32);
  us8 pA1 = *(const us8*)(aSrc1 + 32);
  us8 pB  = *(const us8*)(bSrc  + 32);
  __syncthreads();

  int cur = 0;
  for (int ks=0; ks<8; ++ks){
    // issue loads for tile ks+2 (2-deep: ~2 K-steps of latency cover)
    us8 qA0, qA1, qB;
    if (ks < 6){
      int k0nn = (ks+2)*32;
      qA0 = *(const us8*)(aSrc0 + k0nn);
      qA1 = *(const us8*)(aSrc1 + k0nn);
      qB  = *(const us8*)(bSrc  + k0nn);
    }
    bf16x8 av[4], bv[2];
    #pragma unroll
    for (int i=0;i<4;++i) av[i] = *(bf16x8*)&Asm[cur][(wr*64+i*16+l15)*LDP + l4*8];
    #pragma unroll
    for (int j=0;j<2;++j) bv[j] = *(bf16x8*)&Bsm[cur][(wc*32+j*16+l15)*LDP + l4*8];
    __builtin_amdgcn_s_setprio(1);
    #pragma unroll
    for (int i=0;i<4;++i)
      #pragma unroll
      for (int j=0;j<2;++j)
        acc[i][j] = __builtin_amdgcn_mfma_f32_16x16x32_bf16(av[i], bv[j], acc[i][j], 0,0,0);
    __builtin_amdgcn_s_setprio(0);
    // write pending tile (ks+1) into alternate buffer
    if (ks < 7){
      *(us8*)&Asm[cur^1][aRow0*LDP + aC0*8] = pA0;
      *(us8*)&Asm[cur^1][aRow1*LDP + aC1*8] = pA1;
      *(us8*)&Bsm[cur^1][bRow*LDP + bC*8]   = pB;
    }
    __syncthreads();
    cur ^= 1;
    if (ks < 6){ pA0 = qA0; pA1 = qA1; pB = qB; }
  }

  // epilogue: bilinear pmt contraction + 16-lane reduce
  int c = bx/25, slot = bx%25;
  int rem0 = slot*64;
  float bnbv[2]; int kkv[2], jjv[2];
  #pragma unroll
  for (int j=0;j<2;++j){
    int nl = wc*32 + j*16 + l15;
    int rem = rem0 + nl;
    bnbv[j] = bnb[n0 + nl];
    kkv[j] = rem/40; jjv[j] = rem%40;
  }
  const float* pc  = pmt + (size_t)c*POLY*NBL;
  const float* pcf = pmt + (size_t)(15-c)*POLY*NBL;
  #pragma unroll
  for (int i=0;i<4;++i){
    int mb = m0 + wr*64 + i*16 + l4*4;
    f32x4 s; s[0]=0.f; s[1]=0.f; s[2]=0.f; s[3]=0.f;
    #pragma unroll
    for (int j=0;j<2;++j){
      f32x4 pk = *(const f32x4*)&pc [(size_t)kkv[j]*NBL + mb];
      f32x4 pj = *(const f32x4*)&pcf[(size_t)jjv[j]*NBL + mb];
      #pragma unroll
      for (int q=0;q<4;++q) s[q] += (acc[i][j][q] + bnbv[j]) * pk[q] * pj[q];
    }
    #pragma unroll
    for (int q=0;q<4;++q){
      float t = s[q];
      t += __shfl_xor(t,1); t += __shfl_xor(t,2);
      t += __shfl_xor(t,4); t += __shfl_xor(t,8);
      if (l15==0) red[wc][wr*64 + i*16 + l4*4 + q] = t;
    }
  }
  __syncthreads();
  if (tid < 128){
    float v = red[0][tid] + red[1][tid];
    part[((size_t)(c*NSLOT + slot))*NBL + m0 + tid] = v;   // coalesced (m inner)
  }
}

// ---- final zdot: sum 25 partials, drop l=0 (coalesced reads) ----
__global__ void k_final(const float* __restrict__ part, float* __restrict__ out){
  int j = blockIdx.x*blockDim.x+threadIdx.x;   // c*2046 + r
  if (j >= 16*2046) return;
  int c = j / 2046; int r = j % 2046;
  int bb = r / 1023; int l = r % 1023 + 1;
  size_t m = (size_t)bb*1024 + l;
  float s = 0.f;
  #pragma unroll
  for (int q=0;q<NSLOT;++q) s += part[((size_t)(c*NSLOT + q))*NBL + m];
  out[((size_t)(bb*1023 + (l-1)))*16 + c] = s;
}

extern "C" void kernel_launch(void* const* d_in, const int* in_sizes, int n_in,
                              void* d_out, int out_size, void* d_ws, size_t ws_size,
                              hipStream_t stream) {
  const float* x    = (const float*)d_in[0];
  const float* y    = (const float*)d_in[1];
  const float* cpw  = (const float*)d_in[2];
  const float* cpb  = (const float*)d_in[3];
  const float* nw   = (const float*)d_in[4];
  const float* ipw  = (const float*)d_in[5];
  const float* cvw  = (const float*)d_in[6];
  const float* cvb  = (const float*)d_in[7];
  const float* xpw  = (const float*)d_in[8];
  const float* dtw  = (const float*)d_in[9];
  const float* dtb  = (const float*)d_in[10];
  const float* alog = (const float*)d_in[11];
  const float* dsk  = (const float*)d_in[12];
  const float* opw  = (const float*)d_in[13];
  const float* bnw  = (const float*)d_in[14];
  const float* bnb  = (const float*)d_in[15];

  float* out      = (float*)d_out;
  float* out_zdot = out;                 // 2*1023*16
  float* out_sp   = out + 32736;         // 2*1024*256

  float* ws = (float*)d_ws;
  size_t off = 0;
  // --- overlay region (dead after last out_proj; Wb overlays it in fallback path) ---
  float* u     = ws + off; off += (size_t)NBL*256;            //   524288
  unsigned short* rb = (unsigned short*)(ws + off); off += (size_t)NBL*256/2;   // 262144
  float* xz    = ws + off; off += (size_t)NBL*512;            // 1048576
  float* xc    = ws + off; off += (size_t)NBL*256;            //  524288
  unsigned short* xcb = (unsigned short*)(ws + off); off += (size_t)NBL*256/2;  // 262144
  float* delta = ws + off; off += (size_t)NBL*256;            //  524288
  float* bcm   = ws + off; off += (size_t)NBL*32;             //   65536
  unsigned short* yvb = (unsigned short*)(ws + off); off += (size_t)NBL*256/2;  // 262144
  // overlay total = 3,473,408 floats >= Wb's 3,276,800 -> overlay is safe
  // --- persistent region ---
  float* pmt   = ws + off; off += (size_t)NBL*16*POLY;
  float* part  = ws + off; off += (size_t)NSLOT*NBL*16;
  float* hend  = ws + off; off += (size_t)B_SZ*NCH*256*16;
  float* Pc    = ws + off; off += (size_t)B_SZ*NCH*256*16;
  float* Hinit = ws + off; off += (size_t)B_SZ*NCH*256*16;
  unsigned short* spb  = (unsigned short*)(ws + off); off += (size_t)NBL*256/2;
  // ipwb+opwb hold (IPW_N8+OPW_N8)*8 bf16 = (IPW_N8+OPW_N8)*4 floats
  unsigned short* ipwb = (unsigned short*)(ws + off); off += (size_t)(IPW_N8+OPW_N8)*4;
  unsigned short* wcomb= (unsigned short*)(ws + off); off += (size_t)NL*288*256/2;

  // Wb placement: separate region if ws permits (convert early, off critical path),
  // else overlay the mamba temporaries (convert after the mamba loop). Deterministic.
  int wbEarly = ((off + (size_t)NROWS*256/2)*sizeof(float) <= ws_size) ? 1 : 0;
  unsigned short* Wb = wbEarly ? (unsigned short*)(ws + off) : (unsigned short*)ws;

  unsigned short* opwb = ipwb + (size_t)IPW_N8*8;   // opwb contiguous after ipwb

  int preBlocks = PRE_B0+PRE_B1+PRE_B2+PRE_B3 + (wbEarly ? PRE_B4 : 0);
  k_prologue<<<preBlocks, 256, 0, stream>>>(ipw, opw, dtw, xpw, x, y, cpw, cpb, bnw,
                                            ipwb, wcomb, pmt, u, Wb);

  for (int i=0;i<NL;++i){
    k_rms<<<NBL, 256, 0, stream>>>(u, nw + i*256, rb);
    gemm_bf<<<dim3(8,32), 256, 0, stream>>>(rb, ipwb + (size_t)i*512*256, 512, 256,
                                            nullptr, xz, nullptr, 512, 0, nullptr, nullptr);
    k_convsilu<<<(NBL*64+255)/256, 256, 0, stream>>>(xz, cvw + i*256*4, cvb + i*256, xc, xcb);
    gemm_bf<<<dim3(5,32), 256, 0, stream>>>(xcb, wcomb + (size_t)i*288*256, 288, 256,
                                            dtb + i*256, delta, bcm, 256, 2, nullptr, nullptr);
    k_scan1<<<B_SZ*NCH*16, 256, 0, stream>>>(delta, bcm, xc, alog + (size_t)i*256*16, hend, Pc);
    k_scan2<<<(B_SZ*256*16+255)/256, 256, 0, stream>>>(hend, Pc, Hinit);
    k_scan3<<<B_SZ*NCH*16, 256, 0, stream>>>(delta, bcm, xc, xz, alog + (size_t)i*256*16,
                                             dsk + i*256, Hinit, yvb);
    if (i < NL-1){
      gemm_bf<<<dim3(4,32), 256, 0, stream>>>(yvb, opwb + (size_t)i*256*256, 256, 256,
                                              nullptr, u, nullptr, 256, 1, nullptr, nullptr);
    } else {
      // fused: residual + flip + state_pred store + bf16 copy for b_net
      gemm_bf<<<dim3(4,32), 256, 0, stream>>>(yvb, opwb + (size_t)i*256*256, 256, 256,
                                              nullptr, u, nullptr, 256, 3, out_sp, spb);
    }
  }

  if (!wbEarly){
    // overlay path: u..yvb now dead -> convert bnw into the overlay
    k_f2bf<<<(NROWS*256/8 + 255)/256, 256, 0, stream>>>(bnw, Wb, NROWS*256/8);
  }
  k_bnet_mfma<<<dim3(NROWS/64, NBL/128), 256, 0, stream>>>(spb, Wb, bnb, pmt, part);
  k_final<<<(16*2046+255)/256, 256, 0, stream>>>(part, out_zdot);
}